// Round 25
// baseline (1028.602 us; speedup 1.0000x reference)
//
#include <hip/hip_runtime.h>
#include <math.h>

#define N_NODES 50000
#define N_EDGES 800000
#define IN_DIM 128
#define HID 64
#define OUT_DIM 40
#define HEADS 3
#define HH (HEADS * HID) // 192

__device__ inline float atomicMaxFloat(float* addr, float value) {
    // nonneg floats compare correctly as signed ints; negatives as unsigned ints.
    if (value >= 0.0f)
        return __int_as_float(atomicMax((int*)addr, __float_as_int(value)));
    else
        return __uint_as_float(atomicMin((unsigned int*)addr, __float_as_uint(value)));
}

// ---------------------------------------------------------------- fallback: zero output
__global__ void zero_out_kernel(float* __restrict__ y, int n) {
    int i = blockIdx.x * blockDim.x + threadIdx.x;
    if (i < n) y[i] = 0.f;
}

// ---------------------------------------------------------------- edge-index dtype detect
// int64 data read as int32: odd words are high halves == 0 (values < 50000).
// int32 data: odd words are random node ids. flag=1 -> int32 layout.
__global__ void detect_kernel(const int* __restrict__ raw, int* __restrict__ flag) {
    __shared__ int any;
    if (threadIdx.x == 0) any = 0;
    __syncthreads();
    int nz = 0;
    for (int i = threadIdx.x; i < 2048; i += 256) nz |= (raw[2 * i + 1] != 0);
    if (nz) atomicOr(&any, 1);
    __syncthreads();
    if (threadIdx.x == 0) *flag = any;
}

// Emit clean int32 indices. Single computed-address load (no speculative OOB
// path), clamped so a wrong dtype guess can never produce a faulting index.
__global__ void convert_kernel(const int* __restrict__ raw, const int* __restrict__ flag,
                               int* __restrict__ eidx) {
    int i = blockIdx.x * blockDim.x + threadIdx.x;
    if (i >= 2 * N_EDGES) return;
    int f = *flag;                       // wave-uniform, L2-cached
    int v = raw[f ? i : 2 * i];          // int32 elem, or low word of int64
    v = min(max(v, 0), N_NODES - 1);
    eidx[i] = v;
}

// ---------------------------------------------------------------- fuse pW1@pW2 (no relu between)
__global__ void fuse_mlp_kernel(const float* __restrict__ pW1, const float* __restrict__ pb1,
                                const float* __restrict__ pW2, const float* __restrict__ pb2,
                                float* __restrict__ Wc, float* __restrict__ bc) {
    int idx = blockIdx.x * blockDim.x + threadIdx.x;
    if (idx < HID * OUT_DIM) {
        int d = idx / OUT_DIM, c = idx % OUT_DIM;
        float acc = 0.f;
        for (int k = 0; k < HID; k++) acc = fmaf(pW1[d * HID + k], pW2[k * OUT_DIM + c], acc);
        Wc[idx] = acc;
    } else if (idx < HID * OUT_DIM + OUT_DIM) {
        int c = idx - HID * OUT_DIM;
        float acc = pb2[c];
        for (int k = 0; k < HID; k++) acc = fmaf(pb1[k], pW2[k * OUT_DIM + c], acc);
        bc[c] = acc;
    }
}

// ---------------------------------------------------------------- per-layer init
__global__ void init_layer_kernel(float* __restrict__ amax, float* __restrict__ denom,
                                  float* __restrict__ out, const float* __restrict__ bias) {
    int i = blockIdx.x * blockDim.x + threadIdx.x;
    if (i < N_NODES * HEADS) { amax[i] = -INFINITY; denom[i] = 0.f; }
    if (i < N_NODES * HID) out[i] = bias[i & (HID - 1)];
}

// ---------------------------------------------------------------- node GEMM + score epilogue
// h[n,:] = (relu?)x[n,:] @ W + b ; s_i[n,h] = <h[n,h,:], att_i[h,:]> ; s_j likewise
template <int K, bool RELU_IN, int NPB>
__global__ __launch_bounds__(HH) void node_gemm_kernel(
    const float* __restrict__ x, const float* __restrict__ W, const float* __restrict__ b,
    const float* __restrict__ att, float* __restrict__ h,
    float* __restrict__ s_i, float* __restrict__ s_j) {
    __shared__ float xrow[NPB][K];
    __shared__ float hrow[NPB][HH];
    const int n0 = blockIdx.x * NPB;
    const int t = threadIdx.x;

    for (int i = t; i < NPB * K; i += HH) {
        int r = i / K, c = i % K;
        float v = x[(size_t)(n0 + r) * K + c];
        if (RELU_IN) v = fmaxf(v, 0.f);
        xrow[r][c] = v;
    }
    __syncthreads();

    float acc[NPB];
#pragma unroll
    for (int r = 0; r < NPB; r++) acc[r] = b[t];
    for (int k = 0; k < K; k++) {
        float w = W[k * HH + t];
#pragma unroll
        for (int r = 0; r < NPB; r++) acc[r] = fmaf(xrow[r][k], w, acc[r]);
    }
#pragma unroll
    for (int r = 0; r < NPB; r++) {
        h[(size_t)(n0 + r) * HH + t] = acc[r];
        hrow[r][t] = acc[r];
    }
    __syncthreads();

    const int head = t >> 6, lane = t & 63;
#pragma unroll
    for (int r = 0; r < NPB; r++) {
        float v = hrow[r][head * HID + lane];
        float pi = v * att[head * 2 * HID + lane];
        float pj = v * att[head * 2 * HID + HID + lane];
#pragma unroll
        for (int off = 32; off; off >>= 1) {
            pi += __shfl_down(pi, off);
            pj += __shfl_down(pj, off);
        }
        if (lane == 0) {
            s_i[(n0 + r) * HEADS + head] = pi;
            s_j[(n0 + r) * HEADS + head] = pj;
        }
    }
}

__device__ inline float leaky02(float a) { return (a > 0.f) ? a : 0.2f * a; }

// ---------------------------------------------------------------- edge pass 1: segment max of alpha
__global__ void edge_pass1_kernel(const int* __restrict__ eidx, const float* __restrict__ s_i,
                                  const float* __restrict__ s_j, float* __restrict__ amax) {
    int e = blockIdx.x * blockDim.x + threadIdx.x;
    if (e >= N_EDGES) return;
    int src = eidx[e], dst = eidx[N_EDGES + e];
#pragma unroll
    for (int hh = 0; hh < HEADS; hh++) {
        float a = leaky02(s_i[dst * HEADS + hh] + s_j[src * HEADS + hh]);
        atomicMaxFloat(&amax[dst * HEADS + hh], a);
    }
}

// ---------------------------------------------------------------- edge pass 2: exp + segment sum
__global__ void edge_pass2_kernel(const int* __restrict__ eidx, const float* __restrict__ s_i,
                                  const float* __restrict__ s_j, const float* __restrict__ amax,
                                  float* __restrict__ denom) {
    int e = blockIdx.x * blockDim.x + threadIdx.x;
    if (e >= N_EDGES) return;
    int src = eidx[e], dst = eidx[N_EDGES + e];
#pragma unroll
    for (int hh = 0; hh < HEADS; hh++) {
        float a = leaky02(s_i[dst * HEADS + hh] + s_j[src * HEADS + hh]);
        atomicAdd(&denom[dst * HEADS + hh], expf(a - amax[dst * HEADS + hh]));
    }
}

// ---------------------------------------------------------------- edge pass 3: weighted message scatter
// one 64-lane wave per edge; lane d: out[dst,d] += (1/3) * sum_h h[src,h,d] * ex_h/(denom+eps)
__global__ void edge_pass3_kernel(const int* __restrict__ eidx, const float* __restrict__ h,
                                  const float* __restrict__ s_i, const float* __restrict__ s_j,
                                  const float* __restrict__ amax, const float* __restrict__ denom,
                                  float* __restrict__ out) {
    long long idx = (long long)blockIdx.x * blockDim.x + threadIdx.x;
    int e = (int)(idx >> 6);
    int d = (int)(idx & 63);
    if (e >= N_EDGES) return;
    int src = eidx[e], dst = eidx[N_EDGES + e];
    float w[HEADS];
#pragma unroll
    for (int hh = 0; hh < HEADS; hh++) {
        float a = leaky02(s_i[dst * HEADS + hh] + s_j[src * HEADS + hh]);
        float ex = expf(a - amax[dst * HEADS + hh]);
        w[hh] = ex / (denom[dst * HEADS + hh] + 1e-16f);
    }
    const float* hs = h + (size_t)src * HH;
    float v = hs[d] * w[0] + hs[HID + d] * w[1] + hs[2 * HID + d] * w[2];
    atomicAdd(&out[(size_t)dst * HID + d], v * (1.f / 3.f));
}

// ---------------------------------------------------------------- final: relu -> fused MLP -> log_softmax
__global__ __launch_bounds__(64) void final_mlp_kernel(const float* __restrict__ out2,
                                                       const float* __restrict__ Wc,
                                                       const float* __restrict__ bc,
                                                       float* __restrict__ y) {
    __shared__ float row[HID];
    const int n = blockIdx.x, t = threadIdx.x;
    row[t] = fmaxf(out2[(size_t)n * HID + t], 0.f);
    __syncthreads();
    float l = -INFINITY;
    if (t < OUT_DIM) {
        l = bc[t];
#pragma unroll
        for (int d = 0; d < HID; d++) l = fmaf(row[d], Wc[d * OUT_DIM + t], l);
    }
    float lm = l;
#pragma unroll
    for (int off = 32; off; off >>= 1) lm = fmaxf(lm, __shfl_xor(lm, off));
    float ex = (t < OUT_DIM) ? expf(l - lm) : 0.f;
#pragma unroll
    for (int off = 32; off; off >>= 1) ex += __shfl_xor(ex, off);
    if (t < OUT_DIM) y[(size_t)n * OUT_DIM + t] = l - lm - logf(ex);
}

extern "C" void kernel_launch(void* const* d_in, const int* in_sizes, int n_in,
                              void* d_out, int out_size, void* d_ws, size_t ws_size,
                              hipStream_t stream) {
    float* y = (float*)d_out;

    // ---- workspace budget (fp32 elements) ----
    const size_t OFF_H     = 0;                       // 9,600,000
    const size_t OFF_SI    = OFF_H     + 9600000;     //   150,016
    const size_t OFF_SJ    = OFF_SI    + 150016;      //   150,016
    const size_t OFF_AMAX  = OFF_SJ    + 150016;      //   150,016
    const size_t OFF_DENOM = OFF_AMAX  + 150016;      //   150,016
    const size_t OFF_OUT1  = OFF_DENOM + 150016;      // 3,200,000 (out2 aliases)
    const size_t OFF_WC    = OFF_OUT1  + 3200000;     //     2,560
    const size_t OFF_BC    = OFF_WC    + 2560;        //        64
    const size_t OFF_FLAG  = OFF_BC    + 64;          //        16 (int, padded)
    const size_t OFF_EIDX  = OFF_FLAG  + 16;          // 1,600,000 (int)
    const size_t TOTAL_F32 = OFF_EIDX  + 1600000;     // ~59.4 MB

    // ---- validate EVERY assumption; on any mismatch emit clean zeros ----
    const int expect[15] = {
        N_NODES * IN_DIM,      // x
        2 * N_EDGES,           // edge_index
        N_NODES,               // batch
        IN_DIM * HH, HH,       // W1, b1
        HEADS * 2 * HID, HID,  // att1, bias1
        HID * HH, HH,          // W2, b2
        HEADS * 2 * HID, HID,  // att2, bias2
        HID * HID, HID,        // pW1, pb1
        HID * OUT_DIM, OUT_DIM // pW2, pb2
    };
    bool ok = (n_in >= 15) && (ws_size >= TOTAL_F32 * sizeof(float)) &&
              (out_size == N_NODES * OUT_DIM);
    if (ok)
        for (int i = 0; i < 15; i++) ok = ok && (in_sizes[i] == expect[i]);
    if (!ok) {
        zero_out_kernel<<<(out_size + 255) / 256, 256, 0, stream>>>(y, out_size);
        return;
    }

    const float* x     = (const float*)d_in[0];
    const int*   eiraw = (const int*)d_in[1];
    // d_in[2] = batch (unused by reference)
    const float* W1    = (const float*)d_in[3];
    const float* b1    = (const float*)d_in[4];
    const float* att1  = (const float*)d_in[5];
    const float* bias1 = (const float*)d_in[6];
    const float* W2    = (const float*)d_in[7];
    const float* b2    = (const float*)d_in[8];
    const float* att2  = (const float*)d_in[9];
    const float* bias2 = (const float*)d_in[10];
    const float* pW1   = (const float*)d_in[11];
    const float* pb1   = (const float*)d_in[12];
    const float* pW2   = (const float*)d_in[13];
    const float* pb2   = (const float*)d_in[14];

    float* ws    = (float*)d_ws;
    float* h     = ws + OFF_H;
    float* s_i   = ws + OFF_SI;
    float* s_j   = ws + OFF_SJ;
    float* amax  = ws + OFF_AMAX;
    float* denom = ws + OFF_DENOM;
    float* out1  = ws + OFF_OUT1;
    float* out2  = out1;            // aliased: out1 dead after layer-2 GEMM reads it
    float* Wc    = ws + OFF_WC;
    float* bc    = ws + OFF_BC;
    int*   flag  = (int*)(ws + OFF_FLAG);
    int*   eidx  = (int*)(ws + OFF_EIDX);

    const int initBlocks = (N_NODES * HID + 255) / 256;
    const int eBlocks    = (N_EDGES + 255) / 256;
    const int e64Blocks  = (int)(((long long)N_EDGES * 64 + 255) / 256);

    // edge-index normalization (dtype-robust, clamped)
    detect_kernel<<<1, 256, 0, stream>>>(eiraw, flag);
    convert_kernel<<<(2 * N_EDGES + 255) / 256, 256, 0, stream>>>(eiraw, flag, eidx);

    // fused projection weights
    fuse_mlp_kernel<<<(HID * OUT_DIM + OUT_DIM + 255) / 256, 256, 0, stream>>>(pW1, pb1, pW2, pb2, Wc, bc);

    // ---- layer 1
    init_layer_kernel<<<initBlocks, 256, 0, stream>>>(amax, denom, out1, bias1);
    node_gemm_kernel<IN_DIM, false, 8><<<N_NODES / 8, HH, 0, stream>>>(x, W1, b1, att1, h, s_i, s_j);
    edge_pass1_kernel<<<eBlocks, 256, 0, stream>>>(eidx, s_i, s_j, amax);
    edge_pass2_kernel<<<eBlocks, 256, 0, stream>>>(eidx, s_i, s_j, amax, denom);
    edge_pass3_kernel<<<e64Blocks, 256, 0, stream>>>(eidx, h, s_i, s_j, amax, denom, out1);

    // ---- layer 2 (relu of out1 fused into gemm load; init AFTER gemm so out2 may alias out1)
    node_gemm_kernel<HID, true, 8><<<N_NODES / 8, HH, 0, stream>>>(out1, W2, b2, att2, h, s_i, s_j);
    init_layer_kernel<<<initBlocks, 256, 0, stream>>>(amax, denom, out2, bias2);
    edge_pass1_kernel<<<eBlocks, 256, 0, stream>>>(eidx, s_i, s_j, amax);
    edge_pass2_kernel<<<eBlocks, 256, 0, stream>>>(eidx, s_i, s_j, amax, denom);
    edge_pass3_kernel<<<e64Blocks, 256, 0, stream>>>(eidx, h, s_i, s_j, amax, denom, out2);

    // ---- final fused MLP + log_softmax (relu of out2 fused into load)
    final_mlp_kernel<<<N_NODES, 64, 0, stream>>>(out2, Wc, bc, y);
}